// Round 3
// baseline (3474.837 us; speedup 1.0000x reference)
//
#include <hip/hip_runtime.h>

typedef unsigned short u16;
typedef unsigned int   u32;
typedef unsigned long long u64;
typedef __attribute__((ext_vector_type(8))) short short8;   // 8 x bf16 (4 VGPR)
typedef __attribute__((ext_vector_type(4))) float f32x4;

#define NB   64      // batch
#define TS   512     // timesteps
#define HD   512     // hidden
#define RG   4       // row-groups (16 batch rows each)
#define CG   32      // col-groups (16 h-cols each)
#define NBLK (RG*CG) // 128 persistent blocks

__device__ __forceinline__ u16 f2bf(float x) {
    union { float f; u32 i; } v; v.f = x;
    u32 r = (v.i + 0x7fffu + ((v.i >> 16) & 1u)) >> 16;
    return (u16)r;
}
__device__ __forceinline__ u32 pack2bf(float a, float b) {
    return (u32)f2bf(a) | ((u32)f2bf(b) << 16);
}
__device__ __forceinline__ float sigmf(float x) { return 1.0f / (1.0f + __expf(-x)); }
__device__ __forceinline__ float tanhf_fast(float x) { return 1.0f - 2.0f / (__expf(2.0f * x) + 1.0f); }

__device__ __forceinline__ void g2lds16(const void* g, void* l) {
    __builtin_amdgcn_global_load_lds(
        (const __attribute__((address_space(1))) unsigned int*)g,
        (__attribute__((address_space(3))) unsigned int*)l,
        16, 0, 0);
}

// 8 consecutive f32 (16B aligned) -> short8 bf16 fragment (RNE)
__device__ __forceinline__ short8 cvt_frag(const float* p) {
    const f32x4 lo = *(const f32x4*)p;
    const f32x4 hi = *(const f32x4*)(p + 4);
    union { u32 q[4]; short8 s; } u;
    u.q[0] = pack2bf(lo[0], lo[1]);
    u.q[1] = pack2bf(lo[2], lo[3]);
    u.q[2] = pack2bf(hi[0], hi[1]);
    u.q[3] = pack2bf(hi[2], hi[3]);
    return u.s;
}

// ---- transpose + f32->bf16 convert: in (R x C) f32 -> out (C x R) bf16 ----
__global__ void transpose_cvt_k(const float* __restrict__ in, u16* __restrict__ out,
                                int R, int C) {
    __shared__ float tile[32][33];
    const int c0 = blockIdx.x * 32;
    const int r0 = blockIdx.y * 32;
    const int tx = threadIdx.x & 31;
    const int ty = threadIdx.x >> 5;    // 0..7
#pragma unroll
    for (int i = 0; i < 32; i += 8)
        tile[ty + i][tx] = in[(size_t)(r0 + ty + i) * C + c0 + tx];
    __syncthreads();
#pragma unroll
    for (int i = 0; i < 32; i += 8)
        out[(size_t)(c0 + ty + i) * R + r0 + tx] = f2bf(tile[tx][ty + i]);
}

// ---- persistent fused LSTM ------------------------------------------------
// block (r, cg): batch rows [16r,16r+16), h-cols [16cg,16cg+16)
// wave wv = gate; its 16 gate-cols = wv*512 + cg*16 + [0,16)
// h transport: relaxed AGENT-scope u64 atomics (LLC-coherent, no fences).
__global__ __launch_bounds__(256, 1) void lstm_fused(
    const float* __restrict__ x,    // (64,512,512) f32
    const u16*   __restrict__ WtX,  // (2048,512) bf16 = W_xh^T
    const u16*   __restrict__ WtH,  // (2048,512) bf16 = W_hh^T
    const float* __restrict__ bxh,  // (2048) f32
    const float* __restrict__ bhh,  // (2048) f32
    u64*   __restrict__ hbuf,       // (512 steps, 64 rows, 128 u64) bf16 h
    float* __restrict__ y,          // (64,512,512) f32
    u32*   __restrict__ flags)      // (512,4,32)
{
    const int bid  = blockIdx.x;
    const int r    = bid & 3;
    const int cg   = bid >> 2;
    const int tid  = threadIdx.x;
    const int lane = tid & 63;
    const int wv   = tid >> 6;          // gate index 0..3
    const int m15  = lane & 15;
    const int kq   = lane >> 4;         // quad 0..3
    const int n0   = r * 16;
    const int gcol0 = wv * 512 + cg * 16;

    __shared__ float ldsXf[16 * 516];   // x tile f32, pitch 516 (2064B, 16B-aligned)
    __shared__ float gbuf[4][16][17];
    __shared__ u16   ht[16][16];

    // --- preload W fragments (B-operand: n = lane&15, k = kq*8 + j) ---
    short8 wx[16], wh[16];
    {
        const u16* px = WtX + (size_t)(gcol0 + m15) * 512 + kq * 8;
        const u16* ph = WtH + (size_t)(gcol0 + m15) * 512 + kq * 8;
#pragma unroll
        for (int kc = 0; kc < 16; ++kc) {
            wx[kc] = *(const short8*)(px + kc * 32);
            wh[kc] = *(const short8*)(ph + kc * 32);
        }
    }
    const float bsum = bxh[gcol0 + m15] + bhh[gcol0 + m15];

    // elementwise ownership: thread -> (erow, ecol) of block's 16x16 h tile
    const int erow = tid >> 4;
    const int ecol = tid & 15;
    const int en   = n0 + erow;
    const int hcol = cg * 16 + ecol;
    float cst = 0.0f;

    for (int t = 0; t < TS; ++t) {
        // ---- stage x[:,t,:] rows n0..n0+15 as f32 (2KB/row, 2 insts/row)
#pragma unroll
        for (int j = 0; j < 4; ++j) {
            const int row = wv * 4 + j;
            const float* g0 = x + ((size_t)(n0 + row) * 512 + t) * 512;
            g2lds16(g0 + lane * 4,       ldsXf + row * 516);
            g2lds16(g0 + 256 + lane * 4, ldsXf + row * 516 + 256);
        }
        __syncthreads();

        f32x4 a0 = {0.f,0.f,0.f,0.f}, a1 = {0.f,0.f,0.f,0.f};
        f32x4 a2 = {0.f,0.f,0.f,0.f}, a3 = {0.f,0.f,0.f,0.f};

        // ---- x-part MFMA (cvt f32->bf16 in-register; fills the wait bubble)
        {
            const float* lx = ldsXf + m15 * 516 + kq * 8;
#pragma unroll
            for (int kc = 0; kc < 4; ++kc) {
                short8 f0 = cvt_frag(lx + (4*kc + 0) * 32);
                short8 f1 = cvt_frag(lx + (4*kc + 1) * 32);
                short8 f2 = cvt_frag(lx + (4*kc + 2) * 32);
                short8 f3 = cvt_frag(lx + (4*kc + 3) * 32);
                a0 = __builtin_amdgcn_mfma_f32_16x16x32_bf16(f0, wx[4*kc + 0], a0, 0, 0, 0);
                a1 = __builtin_amdgcn_mfma_f32_16x16x32_bf16(f1, wx[4*kc + 1], a1, 0, 0, 0);
                a2 = __builtin_amdgcn_mfma_f32_16x16x32_bf16(f2, wx[4*kc + 2], a2, 0, 0, 0);
                a3 = __builtin_amdgcn_mfma_f32_16x16x32_bf16(f3, wx[4*kc + 3], a3, 0, 0, 0);
            }
        }

        if (t > 0) {
            // ---- poll producer flags of my row-chain (32 flags, lane-parallel)
            const u32* fl = flags + (size_t)(t - 1) * (RG * CG) + r * CG;
            u32 v;
            do {
                v = __hip_atomic_load(fl + (lane & 31), __ATOMIC_RELAXED,
                                      __HIP_MEMORY_SCOPE_AGENT);
            } while (!__all(v != 0u));

            // ---- load h_{t-1} A-fragments directly (LLC-coherent atomics)
            const u64* hrow = hbuf + (size_t)(t - 1) * (NB * 128)
                            + (size_t)(n0 + m15) * 128 + kq * 2;
            u64 hq[32];
#pragma unroll
            for (int kc = 0; kc < 16; ++kc) {
                hq[2*kc]   = __hip_atomic_load(hrow + kc * 8,     __ATOMIC_RELAXED,
                                               __HIP_MEMORY_SCOPE_AGENT);
                hq[2*kc+1] = __hip_atomic_load(hrow + kc * 8 + 1, __ATOMIC_RELAXED,
                                               __HIP_MEMORY_SCOPE_AGENT);
            }
#pragma unroll
            for (int kc = 0; kc < 4; ++kc) {
                union { u64 q[2]; short8 s; } h0, h1, h2, h3;
                h0.q[0] = hq[8*kc+0]; h0.q[1] = hq[8*kc+1];
                h1.q[0] = hq[8*kc+2]; h1.q[1] = hq[8*kc+3];
                h2.q[0] = hq[8*kc+4]; h2.q[1] = hq[8*kc+5];
                h3.q[0] = hq[8*kc+6]; h3.q[1] = hq[8*kc+7];
                a0 = __builtin_amdgcn_mfma_f32_16x16x32_bf16(h0.s, wh[4*kc + 0], a0, 0, 0, 0);
                a1 = __builtin_amdgcn_mfma_f32_16x16x32_bf16(h1.s, wh[4*kc + 1], a1, 0, 0, 0);
                a2 = __builtin_amdgcn_mfma_f32_16x16x32_bf16(h2.s, wh[4*kc + 2], a2, 0, 0, 0);
                a3 = __builtin_amdgcn_mfma_f32_16x16x32_bf16(h3.s, wh[4*kc + 3], a3, 0, 0, 0);
            }
        }

        // ---- merge gates into LDS (C/D layout: col = lane&15, row = kq*4+reg)
        {
            f32x4 g4 = a0 + a1 + a2 + a3;
#pragma unroll
            for (int j = 0; j < 4; ++j)
                gbuf[wv][kq * 4 + j][m15] = g4[j] + bsum;
        }
        __syncthreads();

        // ---- elementwise LSTM cell (1 element per thread)
        {
            const float gi = gbuf[0][erow][ecol];
            const float gf = gbuf[1][erow][ecol];
            const float gg = gbuf[2][erow][ecol];
            const float go = gbuf[3][erow][ecol];
            const float iv = sigmf(gi);
            const float fv = sigmf(gf);
            const float gv = tanhf_fast(gg);
            const float ov = sigmf(go);
            cst = fv * cst + iv * gv;
            const float hv = ov * tanhf_fast(cst);
            y[((size_t)en * 512 + t) * 512 + hcol] = hv;     // f32 output
            ht[erow][ecol] = f2bf(hv);
        }
        __syncthreads();

        // ---- publish h tile: 64 threads store one u64 each (agent atomics)
        if (tid < 64) {
            const int row = tid >> 2;
            const int c4  = tid & 3;
            const u64 v = *(const u64*)&ht[row][c4 * 4];
            __hip_atomic_store(hbuf + (size_t)t * (NB * 128)
                               + (size_t)(n0 + row) * 128 + cg * 4 + c4, v,
                               __ATOMIC_RELAXED, __HIP_MEMORY_SCOPE_AGENT);
        }
        __syncthreads();   // drains vmcnt(0): stores complete at LLC

        if (t < TS - 1 && tid == 0) {
            __hip_atomic_store(flags + (size_t)t * (RG * CG) + r * CG + cg, 1u,
                               __ATOMIC_RELAXED, __HIP_MEMORY_SCOPE_AGENT);
        }
    }
}

extern "C" void kernel_launch(void* const* d_in, const int* in_sizes, int n_in,
                              void* d_out, int out_size, void* d_ws, size_t ws_size,
                              hipStream_t stream) {
    const float* x   = (const float*)d_in[0];
    const float* wxh = (const float*)d_in[1];
    const float* whh = (const float*)d_in[2];
    const float* bxh = (const float*)d_in[3];
    const float* bhh = (const float*)d_in[4];
    float* y = (float*)d_out;

    char* ws = (char*)d_ws;
    u32* flags = (u32*)ws;                                    // 256 KB
    u16* WtX   = (u16*)(ws + (size_t)(1 << 18));              // 2 MB
    u16* WtH   = (u16*)(ws + (size_t)(1 << 18) + (size_t)2048 * 512 * 2);
    u64* hbuf  = (u64*)(ws + (size_t)(1 << 18) + (size_t)2 * 2048 * 512 * 2);  // 33.6 MB

    (void)hipMemsetAsync(flags, 0, (size_t)TS * RG * CG * sizeof(u32), stream);

    dim3 tgrid(2048 / 32, 512 / 32);
    transpose_cvt_k<<<tgrid, 256, 0, stream>>>(wxh, WtX, 512, 2048);
    transpose_cvt_k<<<tgrid, 256, 0, stream>>>(whh, WtH, 512, 2048);

    lstm_fused<<<dim3(NBLK), dim3(256), 0, stream>>>(x, WtX, WtH, bxh, bhh,
                                                     hbuf, y, flags);
}

// Round 4
// 2142.771 us; speedup vs baseline: 1.6217x; 1.6217x over previous
//
#include <hip/hip_runtime.h>

typedef unsigned short u16;
typedef unsigned int   u32;
typedef unsigned long long u64;
typedef __attribute__((ext_vector_type(8))) short short8;   // 8 x bf16 (4 VGPR)
typedef __attribute__((ext_vector_type(4))) float f32x4;
typedef __attribute__((ext_vector_type(2))) unsigned long long u64x2;

#define NB   64      // batch
#define TS   512     // timesteps
#define HD   512     // hidden
#define RG   4       // row-groups (16 batch rows each)
#define CG   32      // col-groups (16 h-cols each)
#define NBLK (RG*CG) // 128 persistent blocks
#define HP   130     // ldsH pitch in u64 (1040 B, 16B-aligned, even bank spread)

__device__ __forceinline__ u16 f2bf(float x) {
    union { float f; u32 i; } v; v.f = x;
    u32 r = (v.i + 0x7fffu + ((v.i >> 16) & 1u)) >> 16;
    return (u16)r;
}
__device__ __forceinline__ u32 pack2bf(float a, float b) {
    return (u32)f2bf(a) | ((u32)f2bf(b) << 16);
}
__device__ __forceinline__ float sigmf(float x) { return 1.0f / (1.0f + __expf(-x)); }
__device__ __forceinline__ float tanhf_fast(float x) { return 1.0f - 2.0f / (__expf(2.0f * x) + 1.0f); }

// ---- x: f32 -> bf16, elementwise (one-time) -------------------------------
__global__ void cvt_x_k(const float* __restrict__ in, u16* __restrict__ out, int n) {
    int i = (blockIdx.x * blockDim.x + threadIdx.x) * 8;
    const int stride = gridDim.x * blockDim.x * 8;
    for (; i < n; i += stride) {
        const f32x4 a = *(const f32x4*)(in + i);
        const f32x4 b = *(const f32x4*)(in + i + 4);
        u32 q[4];
        q[0] = pack2bf(a[0], a[1]);
        q[1] = pack2bf(a[2], a[3]);
        q[2] = pack2bf(b[0], b[1]);
        q[3] = pack2bf(b[2], b[3]);
        *(f32x4*)(out + i) = *(f32x4*)q;   // 16B store of 8 bf16
    }
}

// ---- transpose + f32->bf16 convert: in (R x C) f32 -> out (C x R) bf16 ----
__global__ void transpose_cvt_k(const float* __restrict__ in, u16* __restrict__ out,
                                int R, int C) {
    __shared__ float tile[32][33];
    const int c0 = blockIdx.x * 32;
    const int r0 = blockIdx.y * 32;
    const int tx = threadIdx.x & 31;
    const int ty = threadIdx.x >> 5;    // 0..7
#pragma unroll
    for (int i = 0; i < 32; i += 8)
        tile[ty + i][tx] = in[(size_t)(r0 + ty + i) * C + c0 + tx];
    __syncthreads();
#pragma unroll
    for (int i = 0; i < 32; i += 8)
        out[(size_t)(c0 + ty + i) * R + r0 + tx] = f2bf(tile[tx][ty + i]);
}

// ---- persistent fused LSTM ------------------------------------------------
// block (r, cg): batch rows [16r,16r+16), h-cols [16cg,16cg+16)
// wave wv = gate; its 16 gate-cols = wv*512 + cg*16 + [0,16)
// h transport: relaxed AGENT-scope u64 atomics (LLC-coherent), 4-slot ring.
// Per-wave quarter loads + LDS share (4x less LLC traffic than all-wave dup).
__global__ __launch_bounds__(256, 1) void lstm_fused(
    const u16*   __restrict__ xbg,  // (64,512,512) bf16
    const u16*   __restrict__ WtX,  // (2048,512) bf16 = W_xh^T
    const u16*   __restrict__ WtH,  // (2048,512) bf16 = W_hh^T
    const float* __restrict__ bxh,  // (2048) f32
    const float* __restrict__ bhh,  // (2048) f32
    u64*   __restrict__ hbuf,       // ring: (4 slots, 64 rows, 128 u64)
    float* __restrict__ y,          // (64,512,512) f32
    u32*   __restrict__ flags)      // (512,4,32) one-shot
{
    const int bid  = blockIdx.x;
    const int r    = bid & 3;
    const int cg   = bid >> 2;
    const int tid  = threadIdx.x;
    const int lane = tid & 63;
    const int wv   = tid >> 6;          // gate index 0..3
    const int m15  = lane & 15;
    const int kq   = lane >> 4;         // quad 0..3
    const int n0   = r * 16;
    const int gcol0 = wv * 512 + cg * 16;

    __shared__ u64   ldsH[16 * HP];     // 16.6 KB staged h tile (bf16 rows)
    __shared__ float gbuf[4][16][17];
    __shared__ u16   ht[16][16];

    // --- preload W fragments (B-operand: n = lane&15, k = kq*8 + j) ---
    short8 wx[16], wh[16];
    {
        const u16* px = WtX + (size_t)(gcol0 + m15) * 512 + kq * 8;
        const u16* ph = WtH + (size_t)(gcol0 + m15) * 512 + kq * 8;
#pragma unroll
        for (int kc = 0; kc < 16; ++kc) {
            wx[kc] = *(const short8*)(px + kc * 32);
            wh[kc] = *(const short8*)(ph + kc * 32);
        }
    }
    const float bsum = bxh[gcol0 + m15] + bhh[gcol0 + m15];

    // elementwise ownership: thread -> (erow, ecol) of block's 16x16 h tile
    const int erow = tid >> 4;
    const int ecol = tid & 15;
    const int en   = n0 + erow;
    const int hcol = cg * 16 + ecol;
    float cst = 0.0f;

    // h staging assignment: wave wv owns local rows [4wv, 4wv+4)
    const int lrow = 4 * wv + (lane >> 4);
    const int c0   = (lane & 15) * 8;       // u64 col within 128-u64 row

    // ---- seed x fragments for t=0 (A-frag: row=m15, k=kq*8+kc*32+j)
    short8 xb[16];
    {
        const u16* xg = xbg + ((size_t)(n0 + m15) * TS + 0) * HD + kq * 8;
#pragma unroll
        for (int kc = 0; kc < 16; ++kc)
            xb[kc] = *(const short8*)(xg + kc * 32);
    }

    for (int t = 0; t < TS; ++t) {
        u64 hq[8];
        if (t > 0) {
            // ---- poll producer flags of my row-chain (lane-parallel)
            const u32* fl = flags + (size_t)(t - 1) * (RG * CG) + r * CG;
            u32 v;
            do {
                v = __hip_atomic_load(fl + (lane & 31), __ATOMIC_RELAXED,
                                      __HIP_MEMORY_SCOPE_AGENT);
            } while (!__all(v != 0u));

            // ---- issue my wave's quarter of h_{t-1}: 8 u64 (one 64B line/lane)
            const u64* gsrc = hbuf + (size_t)((t - 1) & 3) * (NB * 128)
                            + (size_t)(n0 + lrow) * 128 + c0;
#pragma unroll
            for (int i = 0; i < 8; ++i)
                hq[i] = __hip_atomic_load(gsrc + i, __ATOMIC_RELAXED,
                                          __HIP_MEMORY_SCOPE_AGENT);
        }

        // ---- x-part MFMA (prefetched regs; overlaps h-load latency)
        f32x4 a0 = {0.f,0.f,0.f,0.f}, a1 = {0.f,0.f,0.f,0.f};
        f32x4 a2 = {0.f,0.f,0.f,0.f}, a3 = {0.f,0.f,0.f,0.f};
#pragma unroll
        for (int kc = 0; kc < 4; ++kc) {
            a0 = __builtin_amdgcn_mfma_f32_16x16x32_bf16(xb[4*kc + 0], wx[4*kc + 0], a0, 0, 0, 0);
            a1 = __builtin_amdgcn_mfma_f32_16x16x32_bf16(xb[4*kc + 1], wx[4*kc + 1], a1, 0, 0, 0);
            a2 = __builtin_amdgcn_mfma_f32_16x16x32_bf16(xb[4*kc + 2], wx[4*kc + 2], a2, 0, 0, 0);
            a3 = __builtin_amdgcn_mfma_f32_16x16x32_bf16(xb[4*kc + 3], wx[4*kc + 3], a3, 0, 0, 0);
        }

        if (t > 0) {
            // ---- share my quarter via LDS
            u64* ldst = &ldsH[lrow * HP + c0];
            *(u64x2*)(ldst)     = (u64x2){hq[0], hq[1]};
            *(u64x2*)(ldst + 2) = (u64x2){hq[2], hq[3]};
            *(u64x2*)(ldst + 4) = (u64x2){hq[4], hq[5]};
            *(u64x2*)(ldst + 6) = (u64x2){hq[6], hq[7]};
            __syncthreads();                                   // B1

            // ---- h-part MFMA from LDS A-frags
            const u16* lh = (const u16*)ldsH + m15 * (HP * 4) + kq * 8;
#pragma unroll
            for (int kc = 0; kc < 4; ++kc) {
                short8 h0 = *(const short8*)(lh + (4*kc + 0) * 32);
                short8 h1 = *(const short8*)(lh + (4*kc + 1) * 32);
                short8 h2 = *(const short8*)(lh + (4*kc + 2) * 32);
                short8 h3 = *(const short8*)(lh + (4*kc + 3) * 32);
                a0 = __builtin_amdgcn_mfma_f32_16x16x32_bf16(h0, wh[4*kc + 0], a0, 0, 0, 0);
                a1 = __builtin_amdgcn_mfma_f32_16x16x32_bf16(h1, wh[4*kc + 1], a1, 0, 0, 0);
                a2 = __builtin_amdgcn_mfma_f32_16x16x32_bf16(h2, wh[4*kc + 2], a2, 0, 0, 0);
                a3 = __builtin_amdgcn_mfma_f32_16x16x32_bf16(h3, wh[4*kc + 3], a3, 0, 0, 0);
            }
        }

        // ---- merge gates into LDS (C/D layout: col = lane&15, row = kq*4+reg)
        {
            f32x4 g4 = a0 + a1 + a2 + a3;
#pragma unroll
            for (int j = 0; j < 4; ++j)
                gbuf[wv][kq * 4 + j][m15] = g4[j] + bsum;
        }
        __syncthreads();                                       // B2

        // ---- elementwise LSTM cell (1 element per thread)
        {
            const float gi = gbuf[0][erow][ecol];
            const float gf = gbuf[1][erow][ecol];
            const float gg = gbuf[2][erow][ecol];
            const float go = gbuf[3][erow][ecol];
            const float iv = sigmf(gi);
            const float fv = sigmf(gf);
            const float gv = tanhf_fast(gg);
            const float ov = sigmf(go);
            cst = fv * cst + iv * gv;
            const float hv = ov * tanhf_fast(cst);
            y[((size_t)en * 512 + t) * 512 + hcol] = hv;       // f32 output
            ht[erow][ecol] = f2bf(hv);
        }
        __syncthreads();                                       // B3

        // ---- publish h tile: wave0 stores 64 u64 (agent atomics, ring slot)
        if (tid < 64) {
            const int row = tid >> 2;
            const int c4  = tid & 3;
            const u64 v = *(const u64*)&ht[row][c4 * 4];
            __hip_atomic_store(hbuf + (size_t)(t & 3) * (NB * 128)
                               + (size_t)(n0 + row) * 128 + cg * 4 + c4, v,
                               __ATOMIC_RELAXED, __HIP_MEMORY_SCOPE_AGENT);
        }
        __syncthreads();                                       // B4: drain stores

        if (t < TS - 1 && tid == 0) {
            __hip_atomic_store(flags + (size_t)t * (RG * CG) + r * CG + cg, 1u,
                               __ATOMIC_RELAXED, __HIP_MEMORY_SCOPE_AGENT);
        }

        // ---- prefetch x fragments for t+1 (overlaps next poll/handoff)
        if (t + 1 < TS) {
            const u16* xg = xbg + ((size_t)(n0 + m15) * TS + (t + 1)) * HD + kq * 8;
#pragma unroll
            for (int kc = 0; kc < 16; ++kc)
                xb[kc] = *(const short8*)(xg + kc * 32);
        }
    }
}

extern "C" void kernel_launch(void* const* d_in, const int* in_sizes, int n_in,
                              void* d_out, int out_size, void* d_ws, size_t ws_size,
                              hipStream_t stream) {
    const float* x   = (const float*)d_in[0];
    const float* wxh = (const float*)d_in[1];
    const float* whh = (const float*)d_in[2];
    const float* bxh = (const float*)d_in[3];
    const float* bhh = (const float*)d_in[4];
    float* y = (float*)d_out;

    char* ws = (char*)d_ws;
    u32* flags = (u32*)ws;                                    // 256 KB (one-shot)
    u64* hbuf  = (u64*)(ws + (size_t)(1 << 18));              // 256 KB ring (4 slots)
    u16* WtX   = (u16*)(ws + (size_t)(2 << 18));              // 2 MB
    u16* WtH   = (u16*)(ws + (size_t)(2 << 18) + (size_t)2048 * 512 * 2);
    u16* xbg   = (u16*)(ws + (size_t)(2 << 18) + (size_t)2 * 2048 * 512 * 2);  // 33.6 MB

    (void)hipMemsetAsync(flags, 0, (size_t)TS * RG * CG * sizeof(u32), stream);

    cvt_x_k<<<2048, 256, 0, stream>>>(x, xbg, NB * TS * HD);

    dim3 tgrid(2048 / 32, 512 / 32);
    transpose_cvt_k<<<tgrid, 256, 0, stream>>>(wxh, WtX, 512, 2048);
    transpose_cvt_k<<<tgrid, 256, 0, stream>>>(whh, WtH, 512, 2048);

    lstm_fused<<<dim3(NBLK), dim3(256), 0, stream>>>(xbg, WtX, WtH, bxh, bhh,
                                                     hbuf, y, flags);
}